// Round 11
// baseline (488.272 us; speedup 1.0000x reference)
//
#include <hip/hip_runtime.h>

#define N_NODES 1024
#define B_SZ 16
#define F_SZ 50
#define MAGIC 0x5EED0001u

typedef float f32x4 __attribute__((ext_vector_type(4)));

// Single dispatch, producer->consumer handoff via agent-scope atomics.
// Blocks 0-63 (dispatched first, never wait): compute the 16384 port bits
//   exactly once. port_feature_mask is a known constant 0/1 matrix
//   (features 0-22 all-zero; port p sums exactly 7 features); summing only
//   nonzero features in ascending-f order is bitwise identical to the
//   reference's masked accumulation (x + 0.0f == x exactly).
//   Bits packed 4 nodes/word, stored with agent-scope atomics (coherence
//   point), then __threadfence + per-block MAGIC flag.
// All 16384 blocks: issue dir-row load, spin on the 4 flags of their batch
//   (t0 only, s_sleep backoff), then compute one 4 KB output row.
// Replay-safe: flags persist as MAGIC across graph replays -> consumers skip
//   the wait and read bits being rewritten with identical values (inputs are
//   unchanged) -> value-correct. First post-poison replay waits properly.
__global__ __launch_bounds__(256) void fused_kernel(
        const float* __restrict__ nf,
        const int* __restrict__ dir,
        unsigned* __restrict__ bits32,   // 4096 words: batch b = words [b*256, b*256+256)
        unsigned* __restrict__ flags,    // 64 words
        float* __restrict__ out) {
    const int x = blockIdx.x;            // 16384 blocks = (b, i)
    const int t = threadIdx.x;
    const int b = x >> 10;
    const int i = x & (N_NODES - 1);

    // issue this row's dir load before any waiting
    int4 d = ((const int4*)(dir + (size_t)i * N_NODES))[t];

    __shared__ unsigned char sb[256];

    if (x < 64) {
        // ---- producer: node bits for idx = x*256 + t ----
        const int idx = x * 256 + t;
        const float* r = nf + (size_t)idx * F_SZ;
        float f[27];
        #pragma unroll
        for (int q = 0; q < 27; ++q) f[q] = r[23 + q];  // features 23..49

        float a0 = (((((f[0]  + f[1])  + f[3])  + f[6])  + f[10]) + f[15]) + f[16];
        float a1 = (((((f[0]  + f[2])  + f[4])  + f[7])  + f[11]) + f[17]) + f[18];
        float a2 = (((((f[1]  + f[2])  + f[5])  + f[8])  + f[12]) + f[19]) + f[20];
        float a3 = (((((f[3]  + f[4])  + f[5])  + f[9])  + f[13]) + f[21]) + f[22];
        float a4 = (((((f[6]  + f[7])  + f[8])  + f[9])  + f[14]) + f[23]) + f[24];
        float a5 = (((((f[10] + f[11]) + f[12]) + f[13]) + f[14]) + f[25]) + f[26];

        unsigned m = 0;
        m |= (a0 > 0.0f) ? 1u  : 0u;
        m |= (a1 > 0.0f) ? 2u  : 0u;
        m |= (a2 > 0.0f) ? 4u  : 0u;
        m |= (a3 > 0.0f) ? 8u  : 0u;
        m |= (a4 > 0.0f) ? 16u : 0u;
        m |= (a5 > 0.0f) ? 32u : 0u;
        sb[t] = (unsigned char)m;
        __syncthreads();

        if (t < 64) {
            unsigned w = (unsigned)sb[4 * t] |
                         ((unsigned)sb[4 * t + 1] << 8) |
                         ((unsigned)sb[4 * t + 2] << 16) |
                         ((unsigned)sb[4 * t + 3] << 24);
            __hip_atomic_store(&bits32[x * 64 + t], w,
                               __ATOMIC_RELAXED, __HIP_MEMORY_SCOPE_AGENT);
        }
        __threadfence();          // agent-scope: bits visible before flag
        __syncthreads();
        if (t == 0)
            __hip_atomic_store(&flags[x], MAGIC,
                               __ATOMIC_RELEASE, __HIP_MEMORY_SCOPE_AGENT);
    }

    // ---- wait for this batch's 4 producer blocks ----
    if (t == 0) {
        #pragma unroll
        for (int c = 0; c < 4; ++c) {
            while (__hip_atomic_load(&flags[b * 4 + c],
                                     __ATOMIC_ACQUIRE, __HIP_MEMORY_SCOPE_AGENT)
                   != MAGIC)
                __builtin_amdgcn_s_sleep(2);
        }
    }
    __syncthreads();

    // ---- consumer: one 4 KB output row ----
    unsigned w = __hip_atomic_load(&bits32[b * 256 + t],
                                   __ATOMIC_RELAXED, __HIP_MEMORY_SCOPE_AGENT);
    unsigned sw = __hip_atomic_load(&bits32[b * 256 + (i >> 2)],
                                    __ATOMIC_RELAXED, __HIP_MEMORY_SCOPE_AGENT);
    const unsigned s = (sw >> ((i & 3) * 8)) & 0x3fu;

    int dvv[4] = {d.x, d.y, d.z, d.w};
    f32x4 o;
    #pragma unroll
    for (int k = 0; k < 4; ++k) {
        int dval = dvv[k];
        unsigned am = (dval != 6) ? 1u : 0u;
        unsigned ds = (unsigned)min(dval, 5);
        unsigned os = (unsigned)min((dval + 3) % 6, 5);
        unsigned tb = (w >> (8 * k)) & 0x3fu;
        o[k] = ((s >> ds) & (tb >> os) & am & 1u) ? 1.0f : 0.0f;
    }
    *((f32x4*)(out + (size_t)x * N_NODES) + t) = o;
}

extern "C" void kernel_launch(void* const* d_in, const int* in_sizes, int n_in,
                              void* d_out, int out_size, void* d_ws, size_t ws_size,
                              hipStream_t stream) {
    const float* nf  = (const float*)d_in[0];    // (16, 1024, 50) f32
    const int*   dir = (const int*)d_in[1];      // (1024, 1024) i32
    float* out = (float*)d_out;                  // (16, 1024, 1024) f32
    unsigned* bits32 = (unsigned*)d_ws;                        // 16 KB
    unsigned* flags  = (unsigned*)((char*)d_ws + 16384);       // 256 B

    fused_kernel<<<B_SZ * N_NODES, 256, 0, stream>>>(nf, dir, bits32, flags, out);
}

// Round 12
// 21.202 us; speedup vs baseline: 23.0300x; 23.0300x over previous
//
#include <hip/hip_runtime.h>

#define N_NODES 1024
#define B_SZ 16
#define F_SZ 50
#define ROWS_PER_PBLK 256
#define PAD_W 51            // LDS row stride in words; odd -> conflict-free

typedef float f32x4 __attribute__((ext_vector_type(4)));

// Kernel 1: port_has_track bits per (b, n) -> bits[b*N + n].
// Coalesced: each block float2-loads 256 rows (50 KB) CONTIGUOUSLY from
// global (25 loads/thread, fully coalesced; float2 never crosses a row
// boundary since 50 is even), stages into LDS at 51-word row stride
// (odd stride -> conflict-free strided readback), then each thread computes
// its row's 6 port sums from LDS.
// port_feature_mask is a known constant 0/1 matrix: features 0-22 all-zero;
// port p sums exactly 7 features. Summing only nonzero features in
// ascending-f order is bitwise identical to the reference's masked
// accumulation (x + 0.0f == x exactly).
__global__ __launch_bounds__(256) void ports_kernel(
        const float* __restrict__ nf,
        unsigned char* __restrict__ bits) {
    __shared__ float srow[ROWS_PER_PBLK * PAD_W];   // 51 KB

    const int q = blockIdx.x;    // 64 blocks, each owns 256 consecutive rows
    const int t = threadIdx.x;

    // stage: 256 rows * 25 float2 = 6400 float2, thread-interleaved
    const float2* src = (const float2*)(nf + (size_t)q * ROWS_PER_PBLK * F_SZ);
    #pragma unroll
    for (int c = 0; c < 25; ++c) {
        const int g = c * 256 + t;        // float2 index within block chunk
        const int row = g / 25;
        const int w = (g % 25) * 2;
        float2 v = src[g];
        srow[row * PAD_W + w]     = v.x;
        srow[row * PAD_W + w + 1] = v.y;
    }
    __syncthreads();

    const float* r = &srow[t * PAD_W];
    float f[27];
    #pragma unroll
    for (int x = 0; x < 27; ++x) f[x] = r[23 + x];  // features 23..49

    float a0 = (((((f[0]  + f[1])  + f[3])  + f[6])  + f[10]) + f[15]) + f[16];
    float a1 = (((((f[0]  + f[2])  + f[4])  + f[7])  + f[11]) + f[17]) + f[18];
    float a2 = (((((f[1]  + f[2])  + f[5])  + f[8])  + f[12]) + f[19]) + f[20];
    float a3 = (((((f[3]  + f[4])  + f[5])  + f[9])  + f[13]) + f[21]) + f[22];
    float a4 = (((((f[6]  + f[7])  + f[8])  + f[9])  + f[14]) + f[23]) + f[24];
    float a5 = (((((f[10] + f[11]) + f[12]) + f[13]) + f[14]) + f[25]) + f[26];

    unsigned m = 0;
    m |= (a0 > 0.0f) ? 1u  : 0u;
    m |= (a1 > 0.0f) ? 2u  : 0u;
    m |= (a2 > 0.0f) ? 4u  : 0u;
    m |= (a3 > 0.0f) ? 8u  : 0u;
    m |= (a4 > 0.0f) ? 16u : 0u;
    m |= (a5 > 0.0f) ? 32u : 0u;
    bits[q * ROWS_PER_PBLK + t] = (unsigned char)m;
}

// Kernel 2: out[b,i,j] = src_bit(b,i,d) & dst_bit(b,j,o) & (dir != 6)
// Fill-kernel-shaped: one (b,i) row per block (4 KB), one f32x4 per thread,
// plain stores; consecutive blocks write adjacent memory -> dense chip-wide
// sliding write front. dir row shared by 16 blocks spaced 1024 apart
// (same XCD mod 8) -> L2 reuse.
__global__ __launch_bounds__(256) void connect_kernel(
        const int* __restrict__ dir,
        const unsigned char* __restrict__ bits,
        float* __restrict__ out) {
    const int bi = blockIdx.x;          // 16384 blocks = (b, i)
    const int t = threadIdx.x;          // columns [4t, 4t+3]
    const int b = bi >> 10;
    const int i = bi & (N_NODES - 1);

    int4 d = ((const int4*)(dir + (size_t)i * N_NODES))[t];
    uchar4 t4 = ((const uchar4*)(bits + b * N_NODES))[t];
    const unsigned s = bits[b * N_NODES + i];   // block-uniform
    unsigned tv[4] = {t4.x, t4.y, t4.z, t4.w};

    int dvv[4] = {d.x, d.y, d.z, d.w};
    f32x4 o;
    #pragma unroll
    for (int k = 0; k < 4; ++k) {
        int dval = dvv[k];
        unsigned am = (dval != 6) ? 1u : 0u;
        unsigned ds = (unsigned)min(dval, 5);
        unsigned os = (unsigned)min((dval + 3) % 6, 5);
        o[k] = ((s >> ds) & (tv[k] >> os) & am & 1u) ? 1.0f : 0.0f;
    }
    *((f32x4*)(out + (size_t)bi * N_NODES) + t) = o;
}

extern "C" void kernel_launch(void* const* d_in, const int* in_sizes, int n_in,
                              void* d_out, int out_size, void* d_ws, size_t ws_size,
                              hipStream_t stream) {
    const float* nf  = (const float*)d_in[0];    // (16, 1024, 50) f32
    const int*   dir = (const int*)d_in[1];      // (1024, 1024) i32
    float* out = (float*)d_out;                  // (16, 1024, 1024) f32
    unsigned char* bits = (unsigned char*)d_ws;  // 16 KB scratch, [b][n]

    ports_kernel<<<(B_SZ * N_NODES) / ROWS_PER_PBLK, 256, 0, stream>>>(nf, bits);
    connect_kernel<<<B_SZ * N_NODES, 256, 0, stream>>>(dir, bits, out);
}